// Round 1
// baseline (658.398 us; speedup 1.0000x reference)
//
#include <hip/hip_runtime.h>
#include <hip/hip_bf16.h>

// PureGCN forward: h = x@W^T+b; 2x { [+ori] -> LayerNorm -> ReLU -> weighted SpMM }.
// N=100000 nodes, E=1600000 edges, HID=128. fp32 everywhere.
// Strategy: device-built CSR (by dst) each call -> gather-style SpMM (no atomics
// in the 128-wide hot path), wave-per-node LN/SpMM, LDS-broadcast GEMM.

constexpr int N_NODES = 100000;
constexpr int N_EDGES = 1600000;
constexpr int HID     = 128;
constexpr float LN_EPS = 1e-5f;

// ---------------- GEMM: h0[n][j] = sum_k x[n][k]*W[j][k] + b[j] ----------------
// Block: 256 threads = 128 channels x 2 halves; 32 rows per block.
// x tile staged in LDS (all reads are wave-broadcast -> conflict-free);
// W streamed from global as float4 (64 KB, L1/L2-hot).
__global__ __launch_bounds__(256) void k_gemm(const float* __restrict__ x,
                                              const float* __restrict__ W,
                                              const float* __restrict__ bias,
                                              float* __restrict__ h0) {
    __shared__ float Xs[32][HID];
    const int t    = threadIdx.x;
    const int row0 = blockIdx.x * 32;

    // stage 32x128 x-tile: 4096 floats = 1024 float4, 256 threads x 4
    const float4* xg  = (const float4*)(x + (size_t)row0 * HID);
    float4*       xs4 = (float4*)&Xs[0][0];
#pragma unroll
    for (int i = 0; i < 4; ++i) xs4[t + 256 * i] = xg[t + 256 * i];
    __syncthreads();

    const int j    = t & 127;
    const int half = t >> 7;          // 0: rows 0..15, 1: rows 16..31
    const float4* W4 = (const float4*)(W + j * HID);
    const float   bj = bias[j];

    float acc[16];
#pragma unroll
    for (int r = 0; r < 16; ++r) acc[r] = bj;

    for (int k4 = 0; k4 < 32; ++k4) {
        const float4 w = W4[k4];
#pragma unroll
        for (int r = 0; r < 16; ++r) {
            const float4 xv = *(const float4*)&Xs[half * 16 + r][k4 * 4];
            acc[r] += w.x * xv.x + w.y * xv.y + w.z * xv.z + w.w * xv.w;
        }
    }
#pragma unroll
    for (int r = 0; r < 16; ++r)
        h0[(size_t)(row0 + half * 16 + r) * HID + j] = acc[r];
}

// ---------------- CSR build ----------------
__global__ void k_zero(int* __restrict__ p, int n) {
    int i = blockIdx.x * 256 + threadIdx.x;
    if (i < n) p[i] = 0;
}

__global__ void k_hist(const int* __restrict__ ei, int* __restrict__ deg) {
    int e = blockIdx.x * 256 + threadIdx.x;
    if (e < N_EDGES) atomicAdd(&deg[ei[N_EDGES + e]], 1);  // dst row
}

// per-1024-chunk inclusive scan
__global__ __launch_bounds__(1024) void k_scanA(const int* __restrict__ deg,
                                                int* __restrict__ incl,
                                                int* __restrict__ bsums) {
    __shared__ int s[1024];
    const int t   = threadIdx.x;
    const int idx = blockIdx.x * 1024 + t;
    int v = (idx < N_NODES) ? deg[idx] : 0;
    s[t] = v;
    for (int off = 1; off < 1024; off <<= 1) {
        __syncthreads();
        int xv = (t >= off) ? s[t - off] : 0;
        __syncthreads();
        s[t] += xv;
    }
    if (idx < N_NODES) incl[idx] = s[t];
    if (t == 1023) bsums[blockIdx.x] = s[1023];
}

__global__ __launch_bounds__(128) void k_scanB(const int* __restrict__ bsums,
                                               int* __restrict__ boffs) {
    __shared__ int s[128];
    const int t = threadIdx.x;
    int v = (t < 98) ? bsums[t] : 0;   // 98 chunks cover 100352 >= N
    s[t] = v;
    for (int off = 1; off < 128; off <<= 1) {
        __syncthreads();
        int xv = (t >= off) ? s[t - off] : 0;
        __syncthreads();
        s[t] += xv;
    }
    boffs[t] = s[t] - v;               // exclusive
}

__global__ void k_scanC(const int* __restrict__ deg, const int* __restrict__ incl,
                        const int* __restrict__ boffs,
                        int* __restrict__ rp, int* __restrict__ cur) {
    int idx = blockIdx.x * 256 + threadIdx.x;
    if (idx >= N_NODES) return;
    int e = incl[idx] - deg[idx] + boffs[idx >> 10];
    rp[idx]  = e;
    cur[idx] = e;
    if (idx == N_NODES - 1) rp[N_NODES] = e + deg[idx];   // == E
}

__global__ void k_scatter(const int* __restrict__ ei, const float* __restrict__ ef,
                          int* __restrict__ cur,
                          int* __restrict__ col, float* __restrict__ wgt) {
    int e = blockIdx.x * 256 + threadIdx.x;
    if (e >= N_EDGES) return;
    int s = ei[e];
    int d = ei[N_EDGES + e];
    int pos = atomicAdd(&cur[d], 1);
    col[pos] = s;
    wgt[pos] = ef[e];
}

// ---------------- LayerNorm (+optional residual) + ReLU ----------------
// wave per node, lane = 2 channels
__global__ __launch_bounds__(256) void k_ln_relu(const float* __restrict__ hin,
                                                 const float* __restrict__ ori,
                                                 const float* __restrict__ scale,
                                                 const float* __restrict__ bias,
                                                 float* __restrict__ hout) {
    const int wid  = (blockIdx.x * 256 + threadIdx.x) >> 6;
    const int lane = threadIdx.x & 63;
    if (wid >= N_NODES) return;

    float2 v = ((const float2*)hin)[(size_t)wid * 64 + lane];
    if (ori != nullptr) {
        float2 o = ((const float2*)ori)[(size_t)wid * 64 + lane];
        v.x += o.x; v.y += o.y;
    }
    float s  = v.x + v.y;
    float s2 = v.x * v.x + v.y * v.y;
#pragma unroll
    for (int m = 1; m < 64; m <<= 1) {
        s  += __shfl_xor(s, m);
        s2 += __shfl_xor(s2, m);
    }
    const float mu   = s * (1.0f / 128.0f);
    const float var  = s2 * (1.0f / 128.0f) - mu * mu;
    const float rstd = rsqrtf(var + LN_EPS);
    const int c = lane * 2;
    float y0 = (v.x - mu) * rstd * scale[c]     + bias[c];
    float y1 = (v.y - mu) * rstd * scale[c + 1] + bias[c + 1];
    y0 = fmaxf(y0, 0.0f);
    y1 = fmaxf(y1, 0.0f);
    ((float2*)hout)[(size_t)wid * 64 + lane] = make_float2(y0, y1);
}

// ---------------- SpMM gather: out[n] = sum_{e in CSR row n} w_e * h[src_e] ----
__global__ __launch_bounds__(256) void k_spmm(const int* __restrict__ rp,
                                              const int* __restrict__ col,
                                              const float* __restrict__ wgt,
                                              const float* __restrict__ h,
                                              float* __restrict__ out) {
    const int wid  = (blockIdx.x * 256 + threadIdx.x) >> 6;
    const int lane = threadIdx.x & 63;
    if (wid >= N_NODES) return;

    const int beg = rp[wid], end = rp[wid + 1];
    const float2* H = (const float2*)h;
    float2 acc = make_float2(0.0f, 0.0f);
    int e = beg;
    for (; e + 1 < end; e += 2) {
        int   s0 = col[e],     s1 = col[e + 1];
        float w0 = wgt[e],     w1 = wgt[e + 1];
        float2 v0 = H[(size_t)s0 * 64 + lane];
        float2 v1 = H[(size_t)s1 * 64 + lane];
        acc.x += w0 * v0.x + w1 * v1.x;
        acc.y += w0 * v0.y + w1 * v1.y;
    }
    if (e < end) {
        int   s0 = col[e];
        float w0 = wgt[e];
        float2 v0 = H[(size_t)s0 * 64 + lane];
        acc.x += w0 * v0.x;
        acc.y += w0 * v0.y;
    }
    ((float2*)out)[(size_t)wid * 64 + lane] = acc;
}

extern "C" void kernel_launch(void* const* d_in, const int* in_sizes, int n_in,
                              void* d_out, int out_size, void* d_ws, size_t ws_size,
                              hipStream_t stream) {
    const float* x   = (const float*)d_in[0];
    const int*   ei  = (const int*)d_in[1];    // [2, E] int32
    const float* ef  = (const float*)d_in[2];
    const float* W   = (const float*)d_in[3];
    const float* b   = (const float*)d_in[4];
    const float* lns = (const float*)d_in[5];  // [2,128]
    const float* lnb = (const float*)d_in[6];  // [2,128]
    float* out = (float*)d_out;

    // workspace layout (all 4B-aligned; h buffers at 0/51.2MB are 256B-aligned)
    float* h0   = (float*)d_ws;                  // N*128 floats
    float* hact = h0 + (size_t)N_NODES * HID;    // N*128 floats
    int*   deg  = (int*)(hact + (size_t)N_NODES * HID);
    int*   incl = deg + N_NODES;
    int*   bsums = incl + N_NODES;               // 128
    int*   boffs = bsums + 128;                  // 128
    int*   rp   = boffs + 128;                   // N+1
    int*   cur  = rp + (N_NODES + 1);            // N
    int*   col  = cur + N_NODES;                 // E
    float* wgt  = (float*)(col + N_EDGES);       // E

    const int eb = (N_EDGES + 255) / 256;
    const int nb = (N_NODES + 255) / 256;

    // h0 = x @ W^T + b
    k_gemm<<<N_NODES / 32, 256, 0, stream>>>(x, W, b, h0);

    // CSR by dst (rebuilt every call; edge_index may be re-poisoned/restored)
    k_zero<<<nb, 256, 0, stream>>>(deg, N_NODES);
    k_hist<<<eb, 256, 0, stream>>>(ei, deg);
    k_scanA<<<98, 1024, 0, stream>>>(deg, incl, bsums);
    k_scanB<<<1, 128, 0, stream>>>(bsums, boffs);
    k_scanC<<<nb, 256, 0, stream>>>(deg, incl, boffs, rp, cur);
    k_scatter<<<eb, 256, 0, stream>>>(ei, ef, cur, col, wgt);

    // layer 0: LN -> ReLU -> SpMM (SpMM result parked in d_out)
    k_ln_relu<<<(N_NODES * 64 + 255) / 256, 256, 0, stream>>>(h0, nullptr, lns, lnb, hact);
    k_spmm<<<(N_NODES * 64 + 255) / 256, 256, 0, stream>>>(rp, col, wgt, hact, out);

    // layer 1: (+ori) -> LN -> ReLU -> SpMM -> d_out
    k_ln_relu<<<(N_NODES * 64 + 255) / 256, 256, 0, stream>>>(out, h0, lns + HID, lnb + HID, hact);
    k_spmm<<<(N_NODES * 64 + 255) / 256, 256, 0, stream>>>(rp, col, wgt, hact, out);
}

// Round 2
// 513.277 us; speedup vs baseline: 1.2827x; 1.2827x over previous
//
#include <hip/hip_runtime.h>
#include <hip/hip_bf16.h>

// PureGCN forward: h = x@W^T+b; 2x { [+ori] -> LayerNorm -> ReLU -> weighted SpMM }.
// R2: bf16 activation rows (halve gather bytes), LN fused into GEMM epilogue and
// SpMM0 epilogue, packed (col,wgt) int2, scalar-promoted edge loads, 4-wide MLP.

constexpr int N_NODES = 100000;
constexpr int N_EDGES = 1600000;
constexpr int HID     = 128;
constexpr float LN_EPS = 1e-5f;

__device__ inline unsigned pack_bf16x2(float a, float b) {
    unsigned ua = __float_as_uint(a), ub = __float_as_uint(b);
    ua += 0x7fff + ((ua >> 16) & 1);          // RNE
    ub += 0x7fff + ((ub >> 16) & 1);
    return (ua >> 16) | (ub & 0xffff0000u);
}

// ---------------- GEMM + LN0 + ReLU ----------------
// h0 (fp32, pre-LN, needed for residual) and hact (bf16, post-LN/ReLU).
__global__ __launch_bounds__(256) void k_gemm_ln(const float* __restrict__ x,
                                                 const float* __restrict__ W,
                                                 const float* __restrict__ bias,
                                                 const float* __restrict__ lns,
                                                 const float* __restrict__ lnb,
                                                 float* __restrict__ h0,
                                                 unsigned* __restrict__ hact) {
    __shared__ float Xs[32][HID];             // x tile, then reused for h staging
    const int t    = threadIdx.x;
    const int row0 = blockIdx.x * 32;

    const float4* xg  = (const float4*)(x + (size_t)row0 * HID);
    float4*       xs4 = (float4*)&Xs[0][0];
#pragma unroll
    for (int i = 0; i < 4; ++i) xs4[t + 256 * i] = xg[t + 256 * i];
    __syncthreads();

    const int j    = t & 127;
    const int half = t >> 7;                  // rows half*16 .. +15
    const float4* W4 = (const float4*)(W + j * HID);
    const float   bj = bias[j];

    float acc[16];
#pragma unroll
    for (int r = 0; r < 16; ++r) acc[r] = bj;

    for (int k4 = 0; k4 < 32; ++k4) {
        const float4 w = W4[k4];
#pragma unroll
        for (int r = 0; r < 16; ++r) {
            const float4 xv = *(const float4*)&Xs[half * 16 + r][k4 * 4];
            acc[r] += w.x * xv.x + w.y * xv.y + w.z * xv.z + w.w * xv.w;
        }
    }
    // pre-LN h0 to global (residual source)
#pragma unroll
    for (int r = 0; r < 16; ++r)
        h0[(size_t)(row0 + half * 16 + r) * HID + j] = acc[r];

    __syncthreads();                          // everyone done reading x tile
#pragma unroll
    for (int r = 0; r < 16; ++r) Xs[half * 16 + r][j] = acc[r];
    __syncthreads();

    // LN+ReLU: 4 waves x 8 rows, lane = 2 channels
    const int wave = t >> 6, lane = t & 63;
    const int c = lane * 2;
    const float sc0 = lns[c], sc1 = lns[c + 1];
    const float bb0 = lnb[c], bb1 = lnb[c + 1];
#pragma unroll
    for (int r8 = 0; r8 < 8; ++r8) {
        const int row = wave * 8 + r8;
        float2 v = *(const float2*)&Xs[row][c];
        float s  = v.x + v.y;
        float s2 = v.x * v.x + v.y * v.y;
#pragma unroll
        for (int m = 1; m < 64; m <<= 1) {
            s  += __shfl_xor(s, m);
            s2 += __shfl_xor(s2, m);
        }
        const float mu   = s * (1.0f / 128.0f);
        const float var  = s2 * (1.0f / 128.0f) - mu * mu;
        const float rstd = rsqrtf(var + LN_EPS);
        float y0 = fmaxf((v.x - mu) * rstd * sc0 + bb0, 0.0f);
        float y1 = fmaxf((v.y - mu) * rstd * sc1 + bb1, 0.0f);
        hact[(size_t)(row0 + row) * 64 + lane] = pack_bf16x2(y0, y1);
    }
}

// ---------------- CSR build ----------------
__global__ void k_hist(const int* __restrict__ ei, int* __restrict__ deg) {
    int e = blockIdx.x * 256 + threadIdx.x;
    if (e < N_EDGES) atomicAdd(&deg[ei[N_EDGES + e]], 1);  // dst row
}

__global__ __launch_bounds__(1024) void k_scanA(const int* __restrict__ deg,
                                                int* __restrict__ incl,
                                                int* __restrict__ bsums) {
    __shared__ int s[1024];
    const int t   = threadIdx.x;
    const int idx = blockIdx.x * 1024 + t;
    int v = (idx < N_NODES) ? deg[idx] : 0;
    s[t] = v;
    for (int off = 1; off < 1024; off <<= 1) {
        __syncthreads();
        int xv = (t >= off) ? s[t - off] : 0;
        __syncthreads();
        s[t] += xv;
    }
    if (idx < N_NODES) incl[idx] = s[t];
    if (t == 1023) bsums[blockIdx.x] = s[1023];
}

__global__ __launch_bounds__(128) void k_scanB(const int* __restrict__ bsums,
                                               int* __restrict__ boffs) {
    __shared__ int s[128];
    const int t = threadIdx.x;
    int v = (t < 98) ? bsums[t] : 0;
    s[t] = v;
    for (int off = 1; off < 128; off <<= 1) {
        __syncthreads();
        int xv = (t >= off) ? s[t - off] : 0;
        __syncthreads();
        s[t] += xv;
    }
    boffs[t] = s[t] - v;
}

__global__ void k_scanC(const int* __restrict__ deg, const int* __restrict__ incl,
                        const int* __restrict__ boffs,
                        int* __restrict__ rp, int* __restrict__ cur) {
    int idx = blockIdx.x * 256 + threadIdx.x;
    if (idx >= N_NODES) return;
    int e = incl[idx] - deg[idx] + boffs[idx >> 10];
    rp[idx]  = e;
    cur[idx] = e;
    if (idx == N_NODES - 1) rp[N_NODES] = e + deg[idx];
}

__global__ void k_scatter(const int* __restrict__ ei, const float* __restrict__ ef,
                          int* __restrict__ cur, int2* __restrict__ cw) {
    int e = blockIdx.x * 256 + threadIdx.x;
    if (e >= N_EDGES) return;
    int s = ei[e];
    int d = ei[N_EDGES + e];
    int pos = atomicAdd(&cur[d], 1);
    cw[pos] = make_int2(s, __float_as_int(ef[e]));
}

// ---------------- SpMM layer0 + residual + LN1 + ReLU -> bf16 ----------------
__global__ __launch_bounds__(256) void k_spmm_ln(const int* __restrict__ rp,
                                                 const int2* __restrict__ cw,
                                                 const unsigned* __restrict__ Hb,
                                                 const float* __restrict__ ori,
                                                 const float* __restrict__ lns,
                                                 const float* __restrict__ lnb,
                                                 unsigned* __restrict__ hout) {
    const int wid  = (blockIdx.x * 256 + threadIdx.x) >> 6;
    const int lane = threadIdx.x & 63;

    const int beg = __builtin_amdgcn_readfirstlane(rp[wid]);
    const int end = __builtin_amdgcn_readfirstlane(rp[wid + 1]);

    float2 acc = make_float2(0.0f, 0.0f);
    int e = beg;
    for (; e + 4 <= end; e += 4) {
        int2 c0 = cw[e], c1 = cw[e + 1], c2 = cw[e + 2], c3 = cw[e + 3];
        unsigned v0 = Hb[(size_t)c0.x * 64 + lane];
        unsigned v1 = Hb[(size_t)c1.x * 64 + lane];
        unsigned v2 = Hb[(size_t)c2.x * 64 + lane];
        unsigned v3 = Hb[(size_t)c3.x * 64 + lane];
        float w0 = __int_as_float(c0.y), w1 = __int_as_float(c1.y);
        float w2 = __int_as_float(c2.y), w3 = __int_as_float(c3.y);
        acc.x += w0 * __uint_as_float(v0 << 16) + w1 * __uint_as_float(v1 << 16)
               + w2 * __uint_as_float(v2 << 16) + w3 * __uint_as_float(v3 << 16);
        acc.y += w0 * __uint_as_float(v0 & 0xffff0000u) + w1 * __uint_as_float(v1 & 0xffff0000u)
               + w2 * __uint_as_float(v2 & 0xffff0000u) + w3 * __uint_as_float(v3 & 0xffff0000u);
    }
    for (; e < end; ++e) {
        int2 c0 = cw[e];
        unsigned v0 = Hb[(size_t)c0.x * 64 + lane];
        float w0 = __int_as_float(c0.y);
        acc.x += w0 * __uint_as_float(v0 << 16);
        acc.y += w0 * __uint_as_float(v0 & 0xffff0000u);
    }

    // residual + LN + ReLU -> bf16
    float2 o = ((const float2*)ori)[(size_t)wid * 64 + lane];
    float vx = acc.x + o.x, vy = acc.y + o.y;
    float s  = vx + vy;
    float s2 = vx * vx + vy * vy;
#pragma unroll
    for (int m = 1; m < 64; m <<= 1) {
        s  += __shfl_xor(s, m);
        s2 += __shfl_xor(s2, m);
    }
    const float mu   = s * (1.0f / 128.0f);
    const float var  = s2 * (1.0f / 128.0f) - mu * mu;
    const float rstd = rsqrtf(var + LN_EPS);
    const int c = lane * 2;
    float y0 = fmaxf((vx - mu) * rstd * lns[c]     + lnb[c],     0.0f);
    float y1 = fmaxf((vy - mu) * rstd * lns[c + 1] + lnb[c + 1], 0.0f);
    hout[(size_t)wid * 64 + lane] = pack_bf16x2(y0, y1);
}

// ---------------- SpMM final -> fp32 d_out ----------------
__global__ __launch_bounds__(256) void k_spmm_out(const int* __restrict__ rp,
                                                  const int2* __restrict__ cw,
                                                  const unsigned* __restrict__ Hb,
                                                  float* __restrict__ out) {
    const int wid  = (blockIdx.x * 256 + threadIdx.x) >> 6;
    const int lane = threadIdx.x & 63;

    const int beg = __builtin_amdgcn_readfirstlane(rp[wid]);
    const int end = __builtin_amdgcn_readfirstlane(rp[wid + 1]);

    float2 acc = make_float2(0.0f, 0.0f);
    int e = beg;
    for (; e + 4 <= end; e += 4) {
        int2 c0 = cw[e], c1 = cw[e + 1], c2 = cw[e + 2], c3 = cw[e + 3];
        unsigned v0 = Hb[(size_t)c0.x * 64 + lane];
        unsigned v1 = Hb[(size_t)c1.x * 64 + lane];
        unsigned v2 = Hb[(size_t)c2.x * 64 + lane];
        unsigned v3 = Hb[(size_t)c3.x * 64 + lane];
        float w0 = __int_as_float(c0.y), w1 = __int_as_float(c1.y);
        float w2 = __int_as_float(c2.y), w3 = __int_as_float(c3.y);
        acc.x += w0 * __uint_as_float(v0 << 16) + w1 * __uint_as_float(v1 << 16)
               + w2 * __uint_as_float(v2 << 16) + w3 * __uint_as_float(v3 << 16);
        acc.y += w0 * __uint_as_float(v0 & 0xffff0000u) + w1 * __uint_as_float(v1 & 0xffff0000u)
               + w2 * __uint_as_float(v2 & 0xffff0000u) + w3 * __uint_as_float(v3 & 0xffff0000u);
    }
    for (; e < end; ++e) {
        int2 c0 = cw[e];
        unsigned v0 = Hb[(size_t)c0.x * 64 + lane];
        float w0 = __int_as_float(c0.y);
        acc.x += w0 * __uint_as_float(v0 << 16);
        acc.y += w0 * __uint_as_float(v0 & 0xffff0000u);
    }
    ((float2*)out)[(size_t)wid * 64 + lane] = acc;
}

extern "C" void kernel_launch(void* const* d_in, const int* in_sizes, int n_in,
                              void* d_out, int out_size, void* d_ws, size_t ws_size,
                              hipStream_t stream) {
    const float* x   = (const float*)d_in[0];
    const int*   ei  = (const int*)d_in[1];
    const float* ef  = (const float*)d_in[2];
    const float* W   = (const float*)d_in[3];
    const float* b   = (const float*)d_in[4];
    const float* lns = (const float*)d_in[5];
    const float* lnb = (const float*)d_in[6];
    float* out = (float*)d_out;

    // workspace layout
    float*    h0    = (float*)d_ws;                          // N*128 fp32
    unsigned* hact  = (unsigned*)(h0 + (size_t)N_NODES * HID);  // N*64 u32 (bf16x2)
    unsigned* hact2 = hact + (size_t)N_NODES * 64;
    int*   deg   = (int*)(hact2 + (size_t)N_NODES * 64);
    int*   incl  = deg + N_NODES;
    int*   bsums = incl + N_NODES;                           // 128
    int*   boffs = bsums + 128;                              // 128
    int*   rp    = boffs + 128;                              // N+1
    int*   cur   = rp + (N_NODES + 1);                       // N
    int2*  cw    = (int2*)(cur + N_NODES);                   // E (8B each)

    const int eb = (N_EDGES + 255) / 256;
    const int nb = (N_NODES + 255) / 256;
    const int wb = N_NODES * 64 / 256;                       // 25000

    // CSR by dst
    hipMemsetAsync(deg, 0, N_NODES * sizeof(int), stream);
    k_hist<<<eb, 256, 0, stream>>>(ei, deg);
    k_scanA<<<98, 1024, 0, stream>>>(deg, incl, bsums);
    k_scanB<<<1, 128, 0, stream>>>(bsums, boffs);
    k_scanC<<<nb, 256, 0, stream>>>(deg, incl, boffs, rp, cur);
    k_scatter<<<eb, 256, 0, stream>>>(ei, ef, cur, cw);

    // h0 = x@W^T+b ; hact = bf16(relu(LN0(h0)))
    k_gemm_ln<<<N_NODES / 32, 256, 0, stream>>>(x, W, b, lns, lnb, h0, hact);

    // layer 0 SpMM + residual + LN1 + ReLU -> hact2 (bf16)
    k_spmm_ln<<<wb, 256, 0, stream>>>(rp, cw, hact, h0, lns + HID, lnb + HID, hact2);

    // layer 1 SpMM -> d_out (fp32)
    k_spmm_out<<<wb, 256, 0, stream>>>(rp, cw, hact2, out);
}

// Round 3
// 388.239 us; speedup vs baseline: 1.6959x; 1.3221x over previous
//
#include <hip/hip_runtime.h>

// PureGCN forward. R3: MFMA bf16 GEMM (LDS-issue fix), single-pass padded CSR
// (drops hist+scans), h0 parked in d_out. SpMM unchanged from R2 (bf16 rows).

constexpr int N_NODES = 100000;
constexpr int N_EDGES = 1600000;
constexpr int HID     = 128;
constexpr int CAP     = 48;     // padded CSR capacity; max degree ~40 (Poisson 16)
constexpr float LN_EPS = 1e-5f;

typedef __attribute__((ext_vector_type(8))) short short8;   // 8 bf16
typedef __attribute__((ext_vector_type(4))) float floatx4;  // MFMA acc

__device__ inline unsigned pack_bf16x2(float a, float b) {
    unsigned ua = __float_as_uint(a), ub = __float_as_uint(b);
    ua += 0x7fff + ((ua >> 16) & 1);          // RNE
    ub += 0x7fff + ((ub >> 16) & 1);
    return (ua >> 16) | (ub & 0xffff0000u);
}

// ---------------- W fp32 -> bf16 (once per call) ----------------
__global__ void k_prepw(const float* __restrict__ W, unsigned* __restrict__ Wb) {
    int i = blockIdx.x * 256 + threadIdx.x;   // 8192 float2 -> u32
    float2 w = ((const float2*)W)[i];
    Wb[i] = pack_bf16x2(w.x, w.y);
}

// ---------------- padded-CSR scatter (single pass) ----------------
__global__ void k_scatter(const int* __restrict__ ei, const float* __restrict__ ef,
                          int* __restrict__ cnt, int2* __restrict__ cwp) {
    int e = blockIdx.x * 256 + threadIdx.x;
    if (e >= N_EDGES) return;
    int s = ei[e];
    int d = ei[N_EDGES + e];
    int pos = atomicAdd(&cnt[d], 1);
    if (pos < CAP) cwp[(size_t)d * CAP + pos] = make_int2(s, __float_as_int(ef[e]));
}

// ---------------- MFMA GEMM + LN0 + ReLU ----------------
// 64 rows/block, 4 waves; wave w: rows w*16..+15 x all 128 cols (8 MFMA col-tiles).
// h0 (fp32 pre-LN, = d_out scratch) + hact (bf16 post-LN/ReLU).
__global__ __launch_bounds__(256) void k_gemm_mfma(const float* __restrict__ x,
                                                   const unsigned* __restrict__ Wb,
                                                   const float* __restrict__ bias,
                                                   const float* __restrict__ lns,
                                                   const float* __restrict__ lnb,
                                                   float* __restrict__ h0,
                                                   unsigned* __restrict__ hact) {
    // Ws[128][136] bf16 (34816B) + Xs[64][136] bf16 (17408B); Hs[64][132] f32 aliases Ws
    __shared__ __align__(16) char smem[128 * 136 * 2 + 64 * 136 * 2];
    ushort (*Ws)[136] = (ushort(*)[136])smem;
    ushort (*Xs)[136] = (ushort(*)[136])(smem + 128 * 136 * 2);
    float  (*Hs)[132] = (float(*)[132])smem;

    const int t    = threadIdx.x;
    const int row0 = blockIdx.x * 64;

    // stage W: 2048 x 16B (8 bf16) into padded rows
    {
        const uint4* Wg = (const uint4*)Wb;
#pragma unroll
        for (int i = 0; i < 8; ++i) {
            int g = t + 256 * i;              // 0..2047
            int r = g >> 4;
            int c = (g & 15) * 8;
            uint4 v = Wg[g];
            *(uint4*)&Ws[r][c] = v;
        }
    }
    // stage x tile -> bf16
    {
        const float4* xg = (const float4*)x;
        const int base = blockIdx.x * 2048;   // 64 rows * 32 float4
#pragma unroll
        for (int i = 0; i < 8; ++i) {
            int f = t + 256 * i;
            int g = base + f;
            float4 v = make_float4(0.f, 0.f, 0.f, 0.f);
            if (g < N_NODES * 32) v = xg[g];
            int r = f >> 5;
            int c = (f & 31) * 4;
            uint2 p = make_uint2(pack_bf16x2(v.x, v.y), pack_bf16x2(v.z, v.w));
            *(uint2*)&Xs[r][c] = p;
        }
    }
    __syncthreads();

    const int wv   = t >> 6;
    const int l    = t & 63;
    const int mrow = l & 15;
    const int kq   = l >> 4;                  // 0..3

    floatx4 acc[8];
#pragma unroll
    for (int i = 0; i < 8; ++i) acc[i] = (floatx4){0.f, 0.f, 0.f, 0.f};

#pragma unroll
    for (int ks = 0; ks < 4; ++ks) {
        short8 a = *(const short8*)&Xs[wv * 16 + mrow][ks * 32 + kq * 8];
#pragma unroll
        for (int tc = 0; tc < 8; ++tc) {
            short8 b = *(const short8*)&Ws[tc * 16 + mrow][ks * 32 + kq * 8];
            acc[tc] = __builtin_amdgcn_mfma_f32_16x16x32_bf16(a, b, acc[tc], 0, 0, 0);
        }
    }
    __syncthreads();                          // done reading Ws/Xs; Hs may alias

    // C/D layout: col = lane&15, row = (lane>>4)*4 + reg
#pragma unroll
    for (int tc = 0; tc < 8; ++tc)
#pragma unroll
        for (int r = 0; r < 4; ++r)
            Hs[wv * 16 + kq * 4 + r][tc * 16 + mrow] = acc[tc][r];
    __syncthreads();

    // LN+ReLU: wave w handles its 16 rows; lane = 2 channels
    const float2 b2  = ((const float2*)bias)[l];
    const float2 sc2 = ((const float2*)lns)[l];
    const float2 bb2 = ((const float2*)lnb)[l];
    for (int rr = 0; rr < 16; ++rr) {
        const int lrow = wv * 16 + rr;
        const int grow = row0 + lrow;
        if (grow >= N_NODES) break;           // wave-uniform
        float2 v = *(const float2*)&Hs[lrow][l * 2];
        v.x += b2.x; v.y += b2.y;
        ((float2*)h0)[(size_t)grow * 64 + l] = v;   // pre-LN residual source
        float s  = v.x + v.y;
        float s2 = v.x * v.x + v.y * v.y;
#pragma unroll
        for (int m = 1; m < 64; m <<= 1) {
            s  += __shfl_xor(s, m);
            s2 += __shfl_xor(s2, m);
        }
        const float mu   = s * (1.0f / 128.0f);
        const float var  = s2 * (1.0f / 128.0f) - mu * mu;
        const float rstd = rsqrtf(var + LN_EPS);
        float y0 = fmaxf((v.x - mu) * rstd * sc2.x + bb2.x, 0.0f);
        float y1 = fmaxf((v.y - mu) * rstd * sc2.y + bb2.y, 0.0f);
        hact[(size_t)grow * 64 + l] = pack_bf16x2(y0, y1);
    }
}

// ---------------- SpMM layer0 + residual + LN1 + ReLU -> bf16 ----------------
__global__ __launch_bounds__(256) void k_spmm_ln(const int* __restrict__ cnt,
                                                 const int2* __restrict__ cwp,
                                                 const unsigned* __restrict__ Hb,
                                                 const float* __restrict__ ori,
                                                 const float* __restrict__ lns,
                                                 const float* __restrict__ lnb,
                                                 unsigned* __restrict__ hout) {
    const int wid  = (blockIdx.x * 256 + threadIdx.x) >> 6;
    const int lane = threadIdx.x & 63;

    const int deg = __builtin_amdgcn_readfirstlane(min(cnt[wid], CAP));
    const int beg = wid * CAP;
    const int end = beg + deg;

    float2 acc = make_float2(0.0f, 0.0f);
    int e = beg;
    for (; e + 4 <= end; e += 4) {
        int2 c0 = cwp[e], c1 = cwp[e + 1], c2 = cwp[e + 2], c3 = cwp[e + 3];
        unsigned v0 = Hb[(size_t)c0.x * 64 + lane];
        unsigned v1 = Hb[(size_t)c1.x * 64 + lane];
        unsigned v2 = Hb[(size_t)c2.x * 64 + lane];
        unsigned v3 = Hb[(size_t)c3.x * 64 + lane];
        float w0 = __int_as_float(c0.y), w1 = __int_as_float(c1.y);
        float w2 = __int_as_float(c2.y), w3 = __int_as_float(c3.y);
        acc.x += w0 * __uint_as_float(v0 << 16) + w1 * __uint_as_float(v1 << 16)
               + w2 * __uint_as_float(v2 << 16) + w3 * __uint_as_float(v3 << 16);
        acc.y += w0 * __uint_as_float(v0 & 0xffff0000u) + w1 * __uint_as_float(v1 & 0xffff0000u)
               + w2 * __uint_as_float(v2 & 0xffff0000u) + w3 * __uint_as_float(v3 & 0xffff0000u);
    }
    for (; e < end; ++e) {
        int2 c0 = cwp[e];
        unsigned v0 = Hb[(size_t)c0.x * 64 + lane];
        float w0 = __int_as_float(c0.y);
        acc.x += w0 * __uint_as_float(v0 << 16);
        acc.y += w0 * __uint_as_float(v0 & 0xffff0000u);
    }

    float2 o = ((const float2*)ori)[(size_t)wid * 64 + lane];
    float vx = acc.x + o.x, vy = acc.y + o.y;
    float s  = vx + vy;
    float s2 = vx * vx + vy * vy;
#pragma unroll
    for (int m = 1; m < 64; m <<= 1) {
        s  += __shfl_xor(s, m);
        s2 += __shfl_xor(s2, m);
    }
    const float mu   = s * (1.0f / 128.0f);
    const float var  = s2 * (1.0f / 128.0f) - mu * mu;
    const float rstd = rsqrtf(var + LN_EPS);
    const int c = lane * 2;
    float y0 = fmaxf((vx - mu) * rstd * lns[c]     + lnb[c],     0.0f);
    float y1 = fmaxf((vy - mu) * rstd * lns[c + 1] + lnb[c + 1], 0.0f);
    hout[(size_t)wid * 64 + lane] = pack_bf16x2(y0, y1);
}

// ---------------- SpMM final -> fp32 d_out ----------------
__global__ __launch_bounds__(256) void k_spmm_out(const int* __restrict__ cnt,
                                                  const int2* __restrict__ cwp,
                                                  const unsigned* __restrict__ Hb,
                                                  float* __restrict__ out) {
    const int wid  = (blockIdx.x * 256 + threadIdx.x) >> 6;
    const int lane = threadIdx.x & 63;

    const int deg = __builtin_amdgcn_readfirstlane(min(cnt[wid], CAP));
    const int beg = wid * CAP;
    const int end = beg + deg;

    float2 acc = make_float2(0.0f, 0.0f);
    int e = beg;
    for (; e + 4 <= end; e += 4) {
        int2 c0 = cwp[e], c1 = cwp[e + 1], c2 = cwp[e + 2], c3 = cwp[e + 3];
        unsigned v0 = Hb[(size_t)c0.x * 64 + lane];
        unsigned v1 = Hb[(size_t)c1.x * 64 + lane];
        unsigned v2 = Hb[(size_t)c2.x * 64 + lane];
        unsigned v3 = Hb[(size_t)c3.x * 64 + lane];
        float w0 = __int_as_float(c0.y), w1 = __int_as_float(c1.y);
        float w2 = __int_as_float(c2.y), w3 = __int_as_float(c3.y);
        acc.x += w0 * __uint_as_float(v0 << 16) + w1 * __uint_as_float(v1 << 16)
               + w2 * __uint_as_float(v2 << 16) + w3 * __uint_as_float(v3 << 16);
        acc.y += w0 * __uint_as_float(v0 & 0xffff0000u) + w1 * __uint_as_float(v1 & 0xffff0000u)
               + w2 * __uint_as_float(v2 & 0xffff0000u) + w3 * __uint_as_float(v3 & 0xffff0000u);
    }
    for (; e < end; ++e) {
        int2 c0 = cwp[e];
        unsigned v0 = Hb[(size_t)c0.x * 64 + lane];
        float w0 = __int_as_float(c0.y);
        acc.x += w0 * __uint_as_float(v0 << 16);
        acc.y += w0 * __uint_as_float(v0 & 0xffff0000u);
    }
    ((float2*)out)[(size_t)wid * 64 + lane] = acc;
}

extern "C" void kernel_launch(void* const* d_in, const int* in_sizes, int n_in,
                              void* d_out, int out_size, void* d_ws, size_t ws_size,
                              hipStream_t stream) {
    const float* x   = (const float*)d_in[0];
    const int*   ei  = (const int*)d_in[1];
    const float* ef  = (const float*)d_in[2];
    const float* W   = (const float*)d_in[3];
    const float* b   = (const float*)d_in[4];
    const float* lns = (const float*)d_in[5];
    const float* lnb = (const float*)d_in[6];
    float* out = (float*)d_out;

    // h0 (pre-LN fp32) lives in d_out: written by GEMM, read as residual by
    // spmm_ln, then overwritten by the final spmm_out.
    float* h0 = out;

    // workspace: hact 25.6MB + hact2 25.6MB + cnt 0.4MB + Wb 32KB + cwp 38.4MB ~ 90MB
    unsigned* hact  = (unsigned*)d_ws;                       // N*64 u32
    unsigned* hact2 = hact + (size_t)N_NODES * 64;
    int*      cnt   = (int*)(hact2 + (size_t)N_NODES * 64);  // N
    unsigned* Wb    = (unsigned*)(cnt + N_NODES);            // 8192
    int2*     cwp   = (int2*)(Wb + 8192);                    // N*CAP

    const int eb = (N_EDGES + 255) / 256;
    const int wb = N_NODES * 64 / 256;

    hipMemsetAsync(cnt, 0, N_NODES * sizeof(int), stream);
    k_prepw<<<32, 256, 0, stream>>>(W, Wb);
    k_scatter<<<eb, 256, 0, stream>>>(ei, ef, cnt, cwp);

    k_gemm_mfma<<<(N_NODES + 63) / 64, 256, 0, stream>>>(x, Wb, b, lns, lnb, h0, hact);

    k_spmm_ln<<<wb, 256, 0, stream>>>(cnt, cwp, hact, h0, lns + HID, lnb + HID, hact2);
    k_spmm_out<<<wb, 256, 0, stream>>>(cnt, cwp, hact2, out);
}

// Round 4
// 322.978 us; speedup vs baseline: 2.0385x; 1.2021x over previous
//
#include <hip/hip_runtime.h>

// PureGCN forward. R4: two-phase multisplit (k_bin -> k_scan -> k_build) builds a
// dense dst-sorted CSR with coalesced writes, replacing the line-granular random
// scatter (was 112us, ~100MB write traffic). GEMM/LN/SpMM structure from R3.

constexpr int N_NODES = 100000;
constexpr int N_EDGES = 1600000;
constexpr int HID     = 128;
constexpr int NBKT    = (N_NODES + 511) / 512;   // 196 buckets of 512 nodes
constexpr int BCAP    = 9216;                    // bucket capacity; mean 8192, +11 sigma
constexpr float LN_EPS = 1e-5f;

typedef __attribute__((ext_vector_type(8))) short short8;   // 8 bf16
typedef __attribute__((ext_vector_type(4))) float floatx4;  // MFMA acc

__device__ inline unsigned pack_bf16x2(float a, float b) {
    unsigned ua = __float_as_uint(a), ub = __float_as_uint(b);
    ua += 0x7fff + ((ua >> 16) & 1);          // RNE
    ub += 0x7fff + ((ub >> 16) & 1);
    return (ua >> 16) | (ub & 0xffff0000u);
}

// ---------------- W fp32 -> bf16 ----------------
__global__ void k_prepw(const float* __restrict__ W, unsigned* __restrict__ Wb) {
    int i = blockIdx.x * 256 + threadIdx.x;
    float2 w = ((const float2*)W)[i];
    Wb[i] = pack_bf16x2(w.x, w.y);
}

// ---------------- phase 1: bucket edges by dst>>9 (LDS multisplit) ----------------
__global__ __launch_bounds__(256) void k_bin(const int* __restrict__ ei,
                                             const float* __restrict__ ef,
                                             int* __restrict__ gcur,
                                             int* __restrict__ gbufDst,
                                             int2* __restrict__ gbufSW) {
    __shared__ int cnt[NBKT];
    __shared__ int incl[256];
    __shared__ int gbase[NBKT];
    __shared__ int sdst[2048];
    __shared__ int2 ssw[2048];
    const int t = threadIdx.x;

    for (int e0 = blockIdx.x * 2048; e0 < N_EDGES; e0 += gridDim.x * 2048) {
        for (int i = t; i < NBKT; i += 256) cnt[i] = 0;
        __syncthreads();

        const int nE = min(2048, N_EDGES - e0);
        int ed[8], es[8], ep[8]; float ew[8];
        const int base = e0 + t * 8;
        if (base + 8 <= N_EDGES) {
            int4 s0 = *(const int4*)&ei[base];
            int4 s1 = *(const int4*)&ei[base + 4];
            int4 d0 = *(const int4*)&ei[N_EDGES + base];
            int4 d1 = *(const int4*)&ei[N_EDGES + base + 4];
            float4 w0 = *(const float4*)&ef[base];
            float4 w1 = *(const float4*)&ef[base + 4];
            es[0]=s0.x; es[1]=s0.y; es[2]=s0.z; es[3]=s0.w;
            es[4]=s1.x; es[5]=s1.y; es[6]=s1.z; es[7]=s1.w;
            ed[0]=d0.x; ed[1]=d0.y; ed[2]=d0.z; ed[3]=d0.w;
            ed[4]=d1.x; ed[5]=d1.y; ed[6]=d1.z; ed[7]=d1.w;
            ew[0]=w0.x; ew[1]=w0.y; ew[2]=w0.z; ew[3]=w0.w;
            ew[4]=w1.x; ew[5]=w1.y; ew[6]=w1.z; ew[7]=w1.w;
#pragma unroll
            for (int k = 0; k < 8; ++k) ep[k] = atomicAdd(&cnt[ed[k] >> 9], 1);
        } else {
#pragma unroll
            for (int k = 0; k < 8; ++k) {
                int idx = base + k;
                if (idx < N_EDGES) {
                    es[k] = ei[idx]; ed[k] = ei[N_EDGES + idx]; ew[k] = ef[idx];
                    ep[k] = atomicAdd(&cnt[ed[k] >> 9], 1);
                } else ed[k] = -1;
            }
        }
        __syncthreads();

        // inclusive scan of cnt (padded to 256)
        int v = (t < NBKT) ? cnt[t] : 0;
        incl[t] = v;
        for (int o = 1; o < 256; o <<= 1) {
            __syncthreads();
            int u = (t >= o) ? incl[t - o] : 0;
            __syncthreads();
            incl[t] += u;
        }
        __syncthreads();
        if (t < NBKT) gbase[t] = atomicAdd(&gcur[t], v);
        __syncthreads();

        // place edges bucket-sorted in LDS
#pragma unroll
        for (int k = 0; k < 8; ++k) {
            if (ed[k] < 0) continue;
            int b = ed[k] >> 9;
            int idx = incl[b] - cnt[b] + ep[k];
            sdst[idx] = ed[k];
            ssw[idx] = make_int2(es[k], __float_as_int(ew[k]));
        }
        __syncthreads();

        // coalesced append to global bucket segments
        for (int j = t; j < nE; j += 256) {
            int d = sdst[j];
            int b = d >> 9;
            int pos = gbase[b] + (j - (incl[b] - cnt[b]));
            if (pos < BCAP) {
                gbufDst[(size_t)b * BCAP + pos] = d;
                gbufSW [(size_t)b * BCAP + pos] = ssw[j];
            }
        }
        __syncthreads();
    }
}

// ---------------- phase 2a: bucket base scan ----------------
__global__ __launch_bounds__(256) void k_scan(const int* __restrict__ gcur,
                                              int* __restrict__ cbase,
                                              int* __restrict__ rp) {
    __shared__ int s[256];
    const int t = threadIdx.x;
    int v = (t < NBKT) ? min(gcur[t], BCAP) : 0;
    s[t] = v;
    for (int o = 1; o < 256; o <<= 1) {
        __syncthreads();
        int u = (t >= o) ? s[t - o] : 0;
        __syncthreads();
        s[t] += u;
    }
    __syncthreads();
    if (t < NBKT) cbase[t] = s[t] - v;
    if (t == NBKT - 1) rp[N_NODES] = s[t];
}

// ---------------- phase 2b: per-bucket counting sort -> dense CSR ----------------
__global__ __launch_bounds__(512) void k_build(const int* __restrict__ gcur,
                                               const int* __restrict__ cbase,
                                               const int* __restrict__ gbufDst,
                                               const int2* __restrict__ gbufSW,
                                               int* __restrict__ rp,
                                               int2* __restrict__ csr) {
    __shared__ int cnt[512];
    __shared__ int cur[512];
    __shared__ int2 sorted[BCAP];
    const int t     = threadIdx.x;
    const int b     = blockIdx.x;
    const int nbase = b * 512;
    const int nb = min(gcur[b], BCAP);
    const int cb = cbase[b];
    const int*  bd = gbufDst + (size_t)b * BCAP;
    const int2* bs = gbufSW  + (size_t)b * BCAP;

    cnt[t] = 0;
    __syncthreads();
    for (int i = t; i < nb; i += 512) atomicAdd(&cnt[bd[i] - nbase], 1);
    __syncthreads();

    int v = cnt[t];
    for (int o = 1; o < 512; o <<= 1) {
        __syncthreads();
        int u = (t >= o) ? cnt[t - o] : 0;
        __syncthreads();
        cnt[t] += u;
    }
    __syncthreads();
    const int excl = cnt[t] - v;
    cur[t] = excl;
    if (nbase + t < N_NODES) rp[nbase + t] = cb + excl;
    __syncthreads();

    for (int i = t; i < nb; i += 512) {
        int d = bd[i];
        int pos = atomicAdd(&cur[d - nbase], 1);
        sorted[pos] = bs[i];
    }
    __syncthreads();
    for (int i = t; i < nb; i += 512) csr[(size_t)cb + i] = sorted[i];
}

// ---------------- MFMA GEMM + LN0 + ReLU ----------------
__global__ __launch_bounds__(256) void k_gemm_mfma(const float* __restrict__ x,
                                                   const unsigned* __restrict__ Wb,
                                                   const float* __restrict__ bias,
                                                   const float* __restrict__ lns,
                                                   const float* __restrict__ lnb,
                                                   float* __restrict__ h0,
                                                   unsigned* __restrict__ hact) {
    __shared__ __align__(16) char smem[128 * 136 * 2 + 64 * 136 * 2];
    ushort (*Ws)[136] = (ushort(*)[136])smem;
    ushort (*Xs)[136] = (ushort(*)[136])(smem + 128 * 136 * 2);
    float  (*Hs)[132] = (float(*)[132])smem;

    const int t    = threadIdx.x;
    const int row0 = blockIdx.x * 64;

    {
        const uint4* Wg = (const uint4*)Wb;
#pragma unroll
        for (int i = 0; i < 8; ++i) {
            int g = t + 256 * i;
            int r = g >> 4;
            int c = (g & 15) * 8;
            uint4 vv = Wg[g];
            *(uint4*)&Ws[r][c] = vv;
        }
    }
    {
        const float4* xg = (const float4*)x;
        const int base = blockIdx.x * 2048;
#pragma unroll
        for (int i = 0; i < 8; ++i) {
            int f = t + 256 * i;
            int g = base + f;
            float4 vv = make_float4(0.f, 0.f, 0.f, 0.f);
            if (g < N_NODES * 32) vv = xg[g];
            int r = f >> 5;
            int c = (f & 31) * 4;
            uint2 p = make_uint2(pack_bf16x2(vv.x, vv.y), pack_bf16x2(vv.z, vv.w));
            *(uint2*)&Xs[r][c] = p;
        }
    }
    __syncthreads();

    const int wv   = t >> 6;
    const int l    = t & 63;
    const int mrow = l & 15;
    const int kq   = l >> 4;

    floatx4 acc[8];
#pragma unroll
    for (int i = 0; i < 8; ++i) acc[i] = (floatx4){0.f, 0.f, 0.f, 0.f};

#pragma unroll
    for (int ks = 0; ks < 4; ++ks) {
        short8 a = *(const short8*)&Xs[wv * 16 + mrow][ks * 32 + kq * 8];
#pragma unroll
        for (int tc = 0; tc < 8; ++tc) {
            short8 bb = *(const short8*)&Ws[tc * 16 + mrow][ks * 32 + kq * 8];
            acc[tc] = __builtin_amdgcn_mfma_f32_16x16x32_bf16(a, bb, acc[tc], 0, 0, 0);
        }
    }
    __syncthreads();

#pragma unroll
    for (int tc = 0; tc < 8; ++tc)
#pragma unroll
        for (int r = 0; r < 4; ++r)
            Hs[wv * 16 + kq * 4 + r][tc * 16 + mrow] = acc[tc][r];
    __syncthreads();

    const float2 b2  = ((const float2*)bias)[l];
    const float2 sc2 = ((const float2*)lns)[l];
    const float2 bb2 = ((const float2*)lnb)[l];
    for (int rr = 0; rr < 16; ++rr) {
        const int lrow = wv * 16 + rr;
        const int grow = row0 + lrow;
        if (grow >= N_NODES) break;
        float2 vv = *(const float2*)&Hs[lrow][l * 2];
        vv.x += b2.x; vv.y += b2.y;
        ((float2*)h0)[(size_t)grow * 64 + l] = vv;
        float s  = vv.x + vv.y;
        float s2 = vv.x * vv.x + vv.y * vv.y;
#pragma unroll
        for (int m = 1; m < 64; m <<= 1) {
            s  += __shfl_xor(s, m);
            s2 += __shfl_xor(s2, m);
        }
        const float mu   = s * (1.0f / 128.0f);
        const float var  = s2 * (1.0f / 128.0f) - mu * mu;
        const float rstd = rsqrtf(var + LN_EPS);
        float y0 = fmaxf((vv.x - mu) * rstd * sc2.x + bb2.x, 0.0f);
        float y1 = fmaxf((vv.y - mu) * rstd * sc2.y + bb2.y, 0.0f);
        hact[(size_t)grow * 64 + l] = pack_bf16x2(y0, y1);
    }
}

// ---------------- SpMM layer0 + residual + LN1 + ReLU -> bf16 ----------------
__global__ __launch_bounds__(256) void k_spmm_ln(const int* __restrict__ rp,
                                                 const int2* __restrict__ cw,
                                                 const unsigned* __restrict__ Hb,
                                                 const float* __restrict__ ori,
                                                 const float* __restrict__ lns,
                                                 const float* __restrict__ lnb,
                                                 unsigned* __restrict__ hout) {
    const int wid  = (blockIdx.x * 256 + threadIdx.x) >> 6;
    const int lane = threadIdx.x & 63;

    const int beg = __builtin_amdgcn_readfirstlane(rp[wid]);
    const int end = __builtin_amdgcn_readfirstlane(rp[wid + 1]);

    float2 acc = make_float2(0.0f, 0.0f);
    int e = beg;
    for (; e + 4 <= end; e += 4) {
        int2 c0 = cw[e], c1 = cw[e + 1], c2 = cw[e + 2], c3 = cw[e + 3];
        unsigned v0 = Hb[(size_t)c0.x * 64 + lane];
        unsigned v1 = Hb[(size_t)c1.x * 64 + lane];
        unsigned v2 = Hb[(size_t)c2.x * 64 + lane];
        unsigned v3 = Hb[(size_t)c3.x * 64 + lane];
        float w0 = __int_as_float(c0.y), w1 = __int_as_float(c1.y);
        float w2 = __int_as_float(c2.y), w3 = __int_as_float(c3.y);
        acc.x += w0 * __uint_as_float(v0 << 16) + w1 * __uint_as_float(v1 << 16)
               + w2 * __uint_as_float(v2 << 16) + w3 * __uint_as_float(v3 << 16);
        acc.y += w0 * __uint_as_float(v0 & 0xffff0000u) + w1 * __uint_as_float(v1 & 0xffff0000u)
               + w2 * __uint_as_float(v2 & 0xffff0000u) + w3 * __uint_as_float(v3 & 0xffff0000u);
    }
    for (; e < end; ++e) {
        int2 c0 = cw[e];
        unsigned v0 = Hb[(size_t)c0.x * 64 + lane];
        float w0 = __int_as_float(c0.y);
        acc.x += w0 * __uint_as_float(v0 << 16);
        acc.y += w0 * __uint_as_float(v0 & 0xffff0000u);
    }

    float2 o = ((const float2*)ori)[(size_t)wid * 64 + lane];
    float vx = acc.x + o.x, vy = acc.y + o.y;
    float s  = vx + vy;
    float s2 = vx * vx + vy * vy;
#pragma unroll
    for (int m = 1; m < 64; m <<= 1) {
        s  += __shfl_xor(s, m);
        s2 += __shfl_xor(s2, m);
    }
    const float mu   = s * (1.0f / 128.0f);
    const float var  = s2 * (1.0f / 128.0f) - mu * mu;
    const float rstd = rsqrtf(var + LN_EPS);
    const int c = lane * 2;
    float y0 = fmaxf((vx - mu) * rstd * lns[c]     + lnb[c],     0.0f);
    float y1 = fmaxf((vy - mu) * rstd * lns[c + 1] + lnb[c + 1], 0.0f);
    hout[(size_t)wid * 64 + lane] = pack_bf16x2(y0, y1);
}

// ---------------- SpMM final -> fp32 d_out ----------------
__global__ __launch_bounds__(256) void k_spmm_out(const int* __restrict__ rp,
                                                  const int2* __restrict__ cw,
                                                  const unsigned* __restrict__ Hb,
                                                  float* __restrict__ out) {
    const int wid  = (blockIdx.x * 256 + threadIdx.x) >> 6;
    const int lane = threadIdx.x & 63;

    const int beg = __builtin_amdgcn_readfirstlane(rp[wid]);
    const int end = __builtin_amdgcn_readfirstlane(rp[wid + 1]);

    float2 acc = make_float2(0.0f, 0.0f);
    int e = beg;
    for (; e + 4 <= end; e += 4) {
        int2 c0 = cw[e], c1 = cw[e + 1], c2 = cw[e + 2], c3 = cw[e + 3];
        unsigned v0 = Hb[(size_t)c0.x * 64 + lane];
        unsigned v1 = Hb[(size_t)c1.x * 64 + lane];
        unsigned v2 = Hb[(size_t)c2.x * 64 + lane];
        unsigned v3 = Hb[(size_t)c3.x * 64 + lane];
        float w0 = __int_as_float(c0.y), w1 = __int_as_float(c1.y);
        float w2 = __int_as_float(c2.y), w3 = __int_as_float(c3.y);
        acc.x += w0 * __uint_as_float(v0 << 16) + w1 * __uint_as_float(v1 << 16)
               + w2 * __uint_as_float(v2 << 16) + w3 * __uint_as_float(v3 << 16);
        acc.y += w0 * __uint_as_float(v0 & 0xffff0000u) + w1 * __uint_as_float(v1 & 0xffff0000u)
               + w2 * __uint_as_float(v2 & 0xffff0000u) + w3 * __uint_as_float(v3 & 0xffff0000u);
    }
    for (; e < end; ++e) {
        int2 c0 = cw[e];
        unsigned v0 = Hb[(size_t)c0.x * 64 + lane];
        float w0 = __int_as_float(c0.y);
        acc.x += w0 * __uint_as_float(v0 << 16);
        acc.y += w0 * __uint_as_float(v0 & 0xffff0000u);
    }
    ((float2*)out)[(size_t)wid * 64 + lane] = acc;
}

extern "C" void kernel_launch(void* const* d_in, const int* in_sizes, int n_in,
                              void* d_out, int out_size, void* d_ws, size_t ws_size,
                              hipStream_t stream) {
    const float* x   = (const float*)d_in[0];
    const int*   ei  = (const int*)d_in[1];
    const float* ef  = (const float*)d_in[2];
    const float* W   = (const float*)d_in[3];
    const float* b   = (const float*)d_in[4];
    const float* lns = (const float*)d_in[5];
    const float* lnb = (const float*)d_in[6];
    float* out = (float*)d_out;
    float* h0  = out;   // pre-LN h parked in d_out (read as residual, then overwritten)

    // workspace: int2 arrays first (8B alignment), then int arrays
    unsigned* hact  = (unsigned*)d_ws;                          // N*64
    unsigned* hact2 = hact + (size_t)N_NODES * 64;              // N*64
    int2* csr    = (int2*)(hact2 + (size_t)N_NODES * 64);       // E
    int2* gbufSW = csr + N_EDGES;                               // NBKT*BCAP
    unsigned* Wb = (unsigned*)(gbufSW + (size_t)NBKT * BCAP);   // 8192
    int* gcur    = (int*)(Wb + 8192);                           // NBKT
    int* cbase   = gcur + NBKT;                                 // NBKT
    int* rp      = cbase + NBKT;                                // N+1
    int* gbufDst = rp + (N_NODES + 1);                          // NBKT*BCAP

    const int wb = N_NODES * 64 / 256;

    hipMemsetAsync(gcur, 0, NBKT * sizeof(int), stream);
    k_prepw<<<32, 256, 0, stream>>>(W, Wb);
    k_bin<<<256, 256, 0, stream>>>(ei, ef, gcur, gbufDst, gbufSW);
    k_scan<<<1, 256, 0, stream>>>(gcur, cbase, rp);
    k_build<<<NBKT, 512, 0, stream>>>(gcur, cbase, gbufDst, gbufSW, rp, csr);

    k_gemm_mfma<<<(N_NODES + 63) / 64, 256, 0, stream>>>(x, Wb, b, lns, lnb, h0, hact);

    k_spmm_ln<<<wb, 256, 0, stream>>>(rp, csr, hact, h0, lns + HID, lnb + HID, hact2);
    k_spmm_out<<<wb, 256, 0, stream>>>(rp, csr, hact2, out);
}